// Round 5
// baseline (168.923 us; speedup 1.0000x reference)
//
#include <hip/hip_runtime.h>
#include <hip/hip_bf16.h>

#define BS 4096
#define D 256
#define NROW 8192      // 2*BS
#define INV_T 2.0f

typedef short short8 __attribute__((ext_vector_type(8)));
typedef float f32x4 __attribute__((ext_vector_type(4)));

__device__ __forceinline__ unsigned short f2b(float x) {
    __hip_bfloat16 h = __float2bfloat16(x);
    return *reinterpret_cast<unsigned short*>(&h);
}
__device__ __forceinline__ float b2f(unsigned short b) {
    unsigned int u = ((unsigned int)b) << 16;
    return __uint_as_float(u);
}

// K1: normalize rows of zi/zj, convert to bf16, store into W [8192][256].
// Also zeroes rowsum[8192] and accum[2] (ws is poisoned 0xAA each call).
__global__ __launch_bounds__(256) void k_norm(const float* __restrict__ zi,
                                              const float* __restrict__ zj,
                                              unsigned short* __restrict__ W,
                                              float* __restrict__ rowsum,
                                              float* __restrict__ accum) {
    const int gt   = blockIdx.x * 256 + threadIdx.x;
    const int wave = gt >> 6;          // one wave per row, 8192 waves
    const int lane = threadIdx.x & 63;

    const float* src = (wave < BS) ? (zi + (size_t)wave * D)
                                   : (zj + (size_t)(wave - BS) * D);
    float4 v = reinterpret_cast<const float4*>(src)[lane];
    float ss = v.x * v.x + v.y * v.y + v.z * v.z + v.w * v.w;
#pragma unroll
    for (int m = 1; m < 64; m <<= 1) ss += __shfl_xor(ss, m, 64);
    float inv = rsqrtf(ss);

    ushort4 o;
    o.x = f2b(v.x * inv);
    o.y = f2b(v.y * inv);
    o.z = f2b(v.z * inv);
    o.w = f2b(v.w * inv);
    reinterpret_cast<ushort4*>(W + (size_t)wave * D)[lane] = o;

    if (gt < NROW) rowsum[gt] = 0.0f;
    if (gt < 2)    accum[gt]  = 0.0f;
}

// K2: S = 2 * W @ W^T, tile 128x128, K=256 in 4 steps of 64.
// Epilogue: exp(S) with diagonal zeroed, row-reduce, atomicAdd into rowsum.
__global__ __launch_bounds__(256) void k_gemm(const unsigned short* __restrict__ W,
                                              float* __restrict__ rowsum) {
    __shared__ unsigned short lA[128 * 64];
    __shared__ unsigned short lB[128 * 64];

    const int tid  = threadIdx.x;
    const int lane = tid & 63;
    const int w    = tid >> 6;      // wave 0..3
    const int wr   = w >> 1;        // wave row (0..1)
    const int wc   = w & 1;         // wave col (0..1)
    const int rowBase = blockIdx.y * 128;
    const int colBase = blockIdx.x * 128;

    f32x4 acc[4][4] = {};

    for (int kk = 0; kk < 4; ++kk) {
        const int kBase = kk * 64;
        __syncthreads();   // previous compute done before overwrite
#pragma unroll
        for (int c = 0; c < 4; ++c) {
            const int seg = c * 4 + w;                 // 0..15
            const int row = seg * 8 + (lane >> 3);     // 8 rows per segment
            const int col = (lane & 7) * 8;            // 8 bf16 = 16B per lane
            const unsigned short* gA = W + (size_t)(rowBase + row) * D + kBase + col;
            const unsigned short* gB = W + (size_t)(colBase + row) * D + kBase + col;
            __builtin_amdgcn_global_load_lds(
                (const __attribute__((address_space(1))) void*)gA,
                (__attribute__((address_space(3))) void*)(lA + seg * 512), 16, 0, 0);
            __builtin_amdgcn_global_load_lds(
                (const __attribute__((address_space(1))) void*)gB,
                (__attribute__((address_space(3))) void*)(lB + seg * 512), 16, 0, 0);
        }
        __syncthreads();   // staging complete (vmcnt drained by compiler)

#pragma unroll
        for (int ks = 0; ks < 2; ++ks) {
            short8 a[4], b[4];
#pragma unroll
            for (int mi = 0; mi < 4; ++mi) {
                const int r = wr * 64 + mi * 16 + (lane & 15);
                a[mi] = *reinterpret_cast<const short8*>(lA + r * 64 + ks * 32 + (lane >> 4) * 8);
            }
#pragma unroll
            for (int ni = 0; ni < 4; ++ni) {
                const int r = wc * 64 + ni * 16 + (lane & 15);
                b[ni] = *reinterpret_cast<const short8*>(lB + r * 64 + ks * 32 + (lane >> 4) * 8);
            }
#pragma unroll
            for (int mi = 0; mi < 4; ++mi)
#pragma unroll
                for (int ni = 0; ni < 4; ++ni)
                    acc[mi][ni] = __builtin_amdgcn_mfma_f32_16x16x32_bf16(
                        a[mi], b[ni], acc[mi][ni], 0, 0, 0);
        }
    }

    // Epilogue: e = exp(2*s), zero the global diagonal, row-sum, atomic.
    // C/D layout (16x16x32): col = lane&15, row = (lane>>4)*4 + reg.
#pragma unroll
    for (int mi = 0; mi < 4; ++mi) {
#pragma unroll
        for (int j = 0; j < 4; ++j) {
            const int gr = rowBase + wr * 64 + mi * 16 + (lane >> 4) * 4 + j;
            float s = 0.0f;
#pragma unroll
            for (int ni = 0; ni < 4; ++ni) {
                const int gc = colBase + wc * 64 + ni * 16 + (lane & 15);
                float e = (gr == gc) ? 0.0f : __expf(acc[mi][ni][j] * INV_T);
                s += e;
            }
            s += __shfl_xor(s, 1, 64);
            s += __shfl_xor(s, 2, 64);
            s += __shfl_xor(s, 4, 64);
            s += __shfl_xor(s, 8, 64);
            if ((lane & 15) == 0) atomicAdd(&rowsum[gr], s);
        }
    }
}

// K3: lse_sum = sum(log(rowsum)), pos_sum = sum_i 2*dot(u_i, v_i).
__global__ __launch_bounds__(256) void k_finalize(const unsigned short* __restrict__ W,
                                                  const float* __restrict__ rowsum,
                                                  float* __restrict__ accum) {
    const int tid  = blockIdx.x * 256 + threadIdx.x;  // 32 blocks -> 8192 threads
    const int lane = threadIdx.x & 63;

    // logsumexp part
    float l = logf(rowsum[tid]);
#pragma unroll
    for (int m = 1; m < 64; m <<= 1) l += __shfl_xor(l, m, 64);
    if (lane == 0) atomicAdd(&accum[0], l);

    // positive part: 128 global waves, 32 pairs each
    const int wgid = tid >> 6;
    float pacc = 0.0f;
    for (int t = 0; t < 32; ++t) {
        const int i = wgid * 32 + t;
        ushort4 ub = reinterpret_cast<const ushort4*>(W + (size_t)i * D)[lane];
        ushort4 vb = reinterpret_cast<const ushort4*>(W + (size_t)(BS + i) * D)[lane];
        pacc += b2f(ub.x) * b2f(vb.x) + b2f(ub.y) * b2f(vb.y)
              + b2f(ub.z) * b2f(vb.z) + b2f(ub.w) * b2f(vb.w);
    }
#pragma unroll
    for (int m = 1; m < 64; m <<= 1) pacc += __shfl_xor(pacc, m, 64);
    if (lane == 0) atomicAdd(&accum[1], INV_T * pacc);
}

// K4: loss = lse_sum/8192 - pos_sum/4096   (pos appears twice among 8192 rows)
__global__ void k_write(const float* __restrict__ accum, float* __restrict__ out) {
    out[0] = accum[0] * (1.0f / NROW) - accum[1] * (1.0f / BS);
}

extern "C" void kernel_launch(void* const* d_in, const int* in_sizes, int n_in,
                              void* d_out, int out_size, void* d_ws, size_t ws_size,
                              hipStream_t stream) {
    const float* zi = (const float*)d_in[0];
    const float* zj = (const float*)d_in[1];
    float* out = (float*)d_out;

    unsigned short* W = (unsigned short*)d_ws;                        // 4 MB
    float* rowsum = (float*)((char*)d_ws + (size_t)NROW * D * 2);     // 32 KB
    float* accum  = rowsum + NROW;                                    // 8 B

    k_norm<<<NROW / 4, 256, 0, stream>>>(zi, zj, W, rowsum, accum);
    k_gemm<<<dim3(64, 64), 256, 0, stream>>>(W, rowsum);
    k_finalize<<<32, 256, 0, stream>>>(W, rowsum, accum);
    k_write<<<1, 1, 0, stream>>>(accum, out);
}

// Round 9
// 106.983 us; speedup vs baseline: 1.5790x; 1.5790x over previous
//
#include <hip/hip_runtime.h>
#include <hip/hip_bf16.h>

#define BS 4096
#define D 256
#define NROW 8192      // 2*BS
#define INV_T 2.0f

typedef short short8 __attribute__((ext_vector_type(8)));
typedef float f32x4 __attribute__((ext_vector_type(4)));

__device__ __forceinline__ unsigned short f2b(float x) {
    __hip_bfloat16 h = __float2bfloat16(x);
    return *reinterpret_cast<unsigned short*>(&h);
}
__device__ __forceinline__ float b2f(unsigned short b) {
    unsigned int u = ((unsigned int)b) << 16;
    return __uint_as_float(u);
}

// K1: normalize rows of zi/zj, convert to bf16, store into W [8192][256].
// Also zeroes rowsum[8192] and accum[2] (ws is poisoned 0xAA each call).
__global__ __launch_bounds__(256) void k_norm(const float* __restrict__ zi,
                                              const float* __restrict__ zj,
                                              unsigned short* __restrict__ W,
                                              float* __restrict__ rowsum,
                                              float* __restrict__ accum) {
    const int gt   = blockIdx.x * 256 + threadIdx.x;
    const int wave = gt >> 6;          // one wave per row, 8192 waves
    const int lane = threadIdx.x & 63;

    const float* src = (wave < BS) ? (zi + (size_t)wave * D)
                                   : (zj + (size_t)(wave - BS) * D);
    float4 v = reinterpret_cast<const float4*>(src)[lane];
    float ss = v.x * v.x + v.y * v.y + v.z * v.z + v.w * v.w;
#pragma unroll
    for (int m = 1; m < 64; m <<= 1) ss += __shfl_xor(ss, m, 64);
    float inv = rsqrtf(ss);

    ushort4 o;
    o.x = f2b(v.x * inv);
    o.y = f2b(v.y * inv);
    o.z = f2b(v.z * inv);
    o.w = f2b(v.w * inv);
    reinterpret_cast<ushort4*>(W + (size_t)wave * D)[lane] = o;

    if (gt < NROW) rowsum[gt] = 0.0f;
    if (gt < 2)    accum[gt]  = 0.0f;
}

// K2: upper-triangle tiles of G = 2*W@W^T (tile 128x128, K=256 in 4 steps).
// LDS tiles are XOR-swizzled (chunk ^= row&7) to kill the 16-way ds_read_b128
// bank conflict of a 128B-stride row-major layout. global_load_lds writes
// linearly, so the swizzle is applied by permuting the per-lane GLOBAL source
// chunk (involution), and re-applied on the ds_read address (rule 21).
// Off-diag blocks contribute exp-sums to BOTH their rows and cols (symmetry).
__global__ __launch_bounds__(256, 4) void k_gemm(const unsigned short* __restrict__ W,
                                                 float* __restrict__ rowsum) {
    __shared__ unsigned short lA[128 * 64];
    __shared__ unsigned short lB[128 * 64];

    const int tid  = threadIdx.x;
    const int lane = tid & 63;
    const int w    = tid >> 6;      // wave 0..3
    const int wr   = w >> 1;        // wave row (0..1)
    const int wc   = w & 1;         // wave col (0..1)

    // triangular decode: t in [0,2080) -> (bi,bj), 0 <= bi <= bj < 64
    const int t = blockIdx.x;
    const int u = 2079 - t;
    int ri = (int)((sqrtf(8.0f * (float)u + 1.0f) - 1.0f) * 0.5f);
    while ((ri + 1) * (ri + 2) / 2 <= u) ++ri;   // exact correction of float sqrt
    while (ri * (ri + 1) / 2 > u) --ri;
    const int bi = 63 - ri;
    const int bj = 63 - (u - ri * (ri + 1) / 2);
    const int rowBase = bi * 128;
    const int colBase = bj * 128;
    const bool isDiag = (bi == bj);

    f32x4 acc[4][4] = {};

    // per-lane swizzled source chunk: lane l stages phys chunk (row l>>3, c=l&7)
    // which must hold logical chunk (l&7) ^ (row&7)
    const int srcColElems = (((lane & 7) ^ ((lane >> 3) & 7)) * 8);
    const int rowInSeg = (lane >> 3);

    for (int kk = 0; kk < 4; ++kk) {
        const int kBase = kk * 64;
        __syncthreads();   // previous compute done before overwrite
#pragma unroll
        for (int c = 0; c < 4; ++c) {
            const int seg = c * 4 + w;                 // 0..15
            const int row = seg * 8 + rowInSeg;
            const unsigned short* gA = W + (size_t)(rowBase + row) * D + kBase + srcColElems;
            const unsigned short* gB = W + (size_t)(colBase + row) * D + kBase + srcColElems;
            __builtin_amdgcn_global_load_lds(
                (const __attribute__((address_space(1))) void*)gA,
                (__attribute__((address_space(3))) void*)(lA + seg * 512), 16, 0, 0);
            __builtin_amdgcn_global_load_lds(
                (const __attribute__((address_space(1))) void*)gB,
                (__attribute__((address_space(3))) void*)(lB + seg * 512), 16, 0, 0);
        }
        __syncthreads();   // staging complete (vmcnt drained by compiler)

#pragma unroll
        for (int ks = 0; ks < 2; ++ks) {
            short8 a[4], b[4];
            const int swz = lane & 7;                  // == fragment row & 7
            const int logChunk = ks * 4 + (lane >> 4); // logical 16B chunk in row
#pragma unroll
            for (int mi = 0; mi < 4; ++mi) {
                const int r = wr * 64 + mi * 16 + (lane & 15);
                a[mi] = *reinterpret_cast<const short8*>(lA + r * 64 + ((logChunk ^ swz) * 8));
            }
#pragma unroll
            for (int ni = 0; ni < 4; ++ni) {
                const int r = wc * 64 + ni * 16 + (lane & 15);
                b[ni] = *reinterpret_cast<const short8*>(lB + r * 64 + ((logChunk ^ swz) * 8));
            }
#pragma unroll
            for (int mi = 0; mi < 4; ++mi)
#pragma unroll
                for (int ni = 0; ni < 4; ++ni)
                    acc[mi][ni] = __builtin_amdgcn_mfma_f32_16x16x32_bf16(
                        a[mi], b[ni], acc[mi][ni], 0, 0, 0);
        }
    }

    // Epilogue. C/D layout (16x16x32): col = lane&15, row = (lane>>4)*4 + reg.
    float colacc[4] = {0.f, 0.f, 0.f, 0.f};
#pragma unroll
    for (int mi = 0; mi < 4; ++mi) {
#pragma unroll
        for (int j = 0; j < 4; ++j) {
            const int gr = rowBase + wr * 64 + mi * 16 + (lane >> 4) * 4 + j;
            float s = 0.0f;
#pragma unroll
            for (int ni = 0; ni < 4; ++ni) {
                float e;
                if (isDiag) {
                    const int gc = colBase + wc * 64 + ni * 16 + (lane & 15);
                    e = (gr == gc) ? 0.0f : __expf(acc[mi][ni][j] * INV_T);
                } else {
                    e = __expf(acc[mi][ni][j] * INV_T);
                }
                s += e;
                colacc[ni] += e;
            }
            s += __shfl_xor(s, 1, 64);
            s += __shfl_xor(s, 2, 64);
            s += __shfl_xor(s, 4, 64);
            s += __shfl_xor(s, 8, 64);
            if ((lane & 15) == 0) atomicAdd(&rowsum[gr], s);
        }
    }
    if (!isDiag) {   // symmetric contribution: this tile is also tile (bj,bi)
#pragma unroll
        for (int ni = 0; ni < 4; ++ni) {
            float cs = colacc[ni];
            cs += __shfl_xor(cs, 16, 64);
            cs += __shfl_xor(cs, 32, 64);
            if ((lane >> 4) == 0)
                atomicAdd(&rowsum[colBase + wc * 64 + ni * 16 + lane], cs);
        }
    }
}

// K3: lse_sum = sum(log(rowsum)), pos_sum = sum_i 2*dot(u_i, v_i).
__global__ __launch_bounds__(256) void k_finalize(const unsigned short* __restrict__ W,
                                                  const float* __restrict__ rowsum,
                                                  float* __restrict__ accum) {
    const int tid  = blockIdx.x * 256 + threadIdx.x;  // 32 blocks -> 8192 threads
    const int lane = threadIdx.x & 63;

    // logsumexp part
    float l = logf(rowsum[tid]);
#pragma unroll
    for (int m = 1; m < 64; m <<= 1) l += __shfl_xor(l, m, 64);
    if (lane == 0) atomicAdd(&accum[0], l);

    // positive part: 128 global waves, 32 pairs each
    const int wgid = tid >> 6;
    float pacc = 0.0f;
    for (int t = 0; t < 32; ++t) {
        const int i = wgid * 32 + t;
        ushort4 ub = reinterpret_cast<const ushort4*>(W + (size_t)i * D)[lane];
        ushort4 vb = reinterpret_cast<const ushort4*>(W + (size_t)(BS + i) * D)[lane];
        pacc += b2f(ub.x) * b2f(vb.x) + b2f(ub.y) * b2f(vb.y)
              + b2f(ub.z) * b2f(vb.z) + b2f(ub.w) * b2f(vb.w);
    }
#pragma unroll
    for (int m = 1; m < 64; m <<= 1) pacc += __shfl_xor(pacc, m, 64);
    if (lane == 0) atomicAdd(&accum[1], INV_T * pacc);
}

// K4: loss = lse_sum/8192 - pos_sum/4096   (pos appears twice among 8192 rows)
__global__ void k_write(const float* __restrict__ accum, float* __restrict__ out) {
    out[0] = accum[0] * (1.0f / NROW) - accum[1] * (1.0f / BS);
}

extern "C" void kernel_launch(void* const* d_in, const int* in_sizes, int n_in,
                              void* d_out, int out_size, void* d_ws, size_t ws_size,
                              hipStream_t stream) {
    const float* zi = (const float*)d_in[0];
    const float* zj = (const float*)d_in[1];
    float* out = (float*)d_out;

    unsigned short* W = (unsigned short*)d_ws;                        // 4 MB
    float* rowsum = (float*)((char*)d_ws + (size_t)NROW * D * 2);     // 32 KB
    float* accum  = rowsum + NROW;                                    // 8 B

    k_norm<<<NROW / 4, 256, 0, stream>>>(zi, zj, W, rowsum, accum);
    k_gemm<<<2080, 256, 0, stream>>>(W, rowsum);
    k_finalize<<<32, 256, 0, stream>>>(W, rowsum, accum);
    k_write<<<1, 1, 0, stream>>>(accum, out);
}